// Round 22
// baseline (193.420 us; speedup 1.0000x reference)
//
#include <hip/hip_runtime.h>
#include <hip/hip_bf16.h>

#define NN 50000
#define NE 800000
#define PAD 56   // ELL width: max in-degree for Poisson(16)/50K nodes ~38; 56 = +10 sigma

typedef __attribute__((ext_vector_type(8))) short bf16x8;
typedef __attribute__((ext_vector_type(4))) float f32x4;
typedef __attribute__((ext_vector_type(8))) unsigned short u16x8;

__device__ __forceinline__ unsigned short f2bf(float f) {
    __hip_bfloat16 h = __float2bfloat16(f);
    return *(unsigned short*)&h;
}
__device__ __forceinline__ float bf2f(unsigned short u) {
    unsigned int w = ((unsigned int)u) << 16;
    return __uint_as_float(w);
}

// split 8 consecutive floats into bf16 hi/lo fragments
__device__ __forceinline__ void split8(const float* __restrict__ p, bf16x8& h8, bf16x8& l8) {
    float4 v0 = *(const float4*)p;
    float4 v1 = *(const float4*)(p + 4);
    float f[8] = {v0.x, v0.y, v0.z, v0.w, v1.x, v1.y, v1.z, v1.w};
#pragma unroll
    for (int i = 0; i < 8; ++i) {
        unsigned short h = f2bf(f[i]);
        h8[i] = (short)h;
        l8[i] = (short)f2bf(f[i] - bf2f(h));
    }
}

// ================= phase 1 "hists": src/dst LDS histograms | gemm0 | W packing =================
#define SRC_BLK 64
#define SRC_CHUNK 12500   // NE / SRC_BLK
#define DST_BLK 160
#define DST_CHUNK 5000    // NE / DST_BLK
#define DEG_WORDS 12500   // NN/4 u32 words, 4 u8 bins per word (50KB LDS)
#define GEMM0_BLK 782     // ceil(NN/64), 16 rows/wave
#define CVW_ELEMS 57344   // fcW + fc2W + W1 (3*16384) + W2 (8192)
#define CVW_BLK 224

__global__ __launch_bounds__(256) void hists_kernel(
    const int* __restrict__ src, const int* __restrict__ dst,
    unsigned* __restrict__ psrc, unsigned* __restrict__ pdst,
    const float* __restrict__ x, const float* __restrict__ W0, unsigned short* __restrict__ Hb,
    const float* __restrict__ fcW, const float* __restrict__ fc2W,
    const float* __restrict__ W1, const float* __restrict__ W2,
    unsigned short* __restrict__ wp_hi, unsigned short* __restrict__ wp_lo) {
    __shared__ unsigned hist[DEG_WORDS];   // 50KB (reused as W0 staging in gemm0 branch)
    const int bid = blockIdx.x;
    const int tid = threadIdx.x;
    if (bid < SRC_BLK + DST_BLK) {
        const bool isSrc = bid < SRC_BLK;
        const int dblk = isSrc ? bid : bid - SRC_BLK;
        const int chunk = isSrc ? SRC_CHUNK : DST_CHUNK;
        const int* ep = isSrc ? (src + dblk * SRC_CHUNK) : (dst + dblk * DST_CHUNK);
        unsigned* outp = (isSrc ? psrc : pdst) + (size_t)dblk * DEG_WORDS;
        for (int i = tid; i < DEG_WORDS; i += 256) hist[i] = 0;
        __syncthreads();
        const int4* sp = (const int4*)ep;
        for (int i = tid; i < chunk / 4; i += 256) {
            int4 s = sp[i];
            atomicAdd(&hist[s.x >> 2], 1u << ((s.x & 3) * 8));
            atomicAdd(&hist[s.y >> 2], 1u << ((s.y & 3) * 8));
            atomicAdd(&hist[s.z >> 2], 1u << ((s.z & 3) * 8));
            atomicAdd(&hist[s.w >> 2], 1u << ((s.w & 3) * 8));
        }
        __syncthreads();
        for (int i = tid; i < DEG_WORDS; i += 256) outp[i] = hist[i];
    } else if (bid < SRC_BLK + DST_BLK + CVW_BLK) {
        int t = (bid - SRC_BLK - DST_BLK) * 256 + tid;
        if (t < CVW_ELEMS) {
            int mi = (t < 16384) ? 0 : (t < 32768) ? 1 : (t < 49152) ? 2 : 3;
            int beg = mi * 16384;
            int Cm = (mi == 3) ? 64 : 128;
            int loc = t - beg;
            int k = loc / Cm, c = loc % Cm;
            float v;
            switch (mi) {
                case 0: v = fcW[loc]; break;
                case 1: v = fc2W[loc]; break;
                case 2: v = W1[loc]; break;
                default: v = W2[loc]; break;
            }
            unsigned short h = f2bf(v);
            unsigned short l = f2bf(v - bf2f(h));
            int off = (((c >> 4) * 4 + (k >> 5)) * 64 + ((k & 31) >> 3) * 16 + (c & 15)) * 8 + (k & 7);
            wp_hi[beg + off] = h;
            wp_lo[beg + off] = l;
        }
    } else {
        // ---- gemm0: Hb = bf16(x @ W0), 16 rows/wave; W0 LDS-staged transposed [n][36] ----
        float* wbuf = (float*)hist;    // 128*36 floats = 18.4KB (fits in 50KB)
        const int gb = bid - SRC_BLK - DST_BLK - CVW_BLK;
        const int wave = tid >> 6;
        const int lane = tid & 63;
        const int m = lane & 15, kg = lane >> 4;
        const int r0 = gb * 64 + wave * 16;
        int ar = r0 + m;
        ar = (ar < NN) ? ar : (NN - 1);

        bf16x8 ah[4], al[4];
#pragma unroll
        for (int ks = 0; ks < 4; ++ks)
            split8(&x[(size_t)ar * 128 + ks * 32 + kg * 8], ah[ks], al[ks]);

        f32x4 acc[8];
#pragma unroll
        for (int ct = 0; ct < 8; ++ct) acc[ct] = (f32x4){0.f, 0.f, 0.f, 0.f};

        for (int ks = 0; ks < 4; ++ks) {
            __syncthreads();
            // stage W0 k-chunk [ks*32, ks*32+32) transposed: wbuf[n*36 + kk]
            const float4* wsrc = (const float4*)(W0 + (size_t)ks * 32 * 128);
            for (int t = tid; t < 1024; t += 256) {
                float4 v = wsrc[t];
                const int kk = t >> 5;          // row 0..31 within chunk
                const int n0 = (t & 31) * 4;
                wbuf[(n0 + 0) * 36 + kk] = v.x;
                wbuf[(n0 + 1) * 36 + kk] = v.y;
                wbuf[(n0 + 2) * 36 + kk] = v.z;
                wbuf[(n0 + 3) * 36 + kk] = v.w;
            }
            __syncthreads();
#pragma unroll
            for (int ct = 0; ct < 8; ++ct) {
                const int n = ct * 16 + m;
                const float* wp = &wbuf[n * 36 + kg * 8];
                bf16x8 bh, bl;
#pragma unroll
                for (int i = 0; i < 8; ++i) {
                    const float wv = wp[i];
                    unsigned short h = f2bf(wv);
                    bh[i] = (short)h;
                    bl[i] = (short)f2bf(wv - bf2f(h));
                }
                acc[ct] = __builtin_amdgcn_mfma_f32_16x16x32_bf16(ah[ks], bh, acc[ct], 0, 0, 0);
                acc[ct] = __builtin_amdgcn_mfma_f32_16x16x32_bf16(al[ks], bh, acc[ct], 0, 0, 0);
                acc[ct] = __builtin_amdgcn_mfma_f32_16x16x32_bf16(ah[ks], bl, acc[ct], 0, 0, 0);
            }
        }
#pragma unroll
        for (int ct = 0; ct < 8; ++ct) {
            const int n = ct * 16 + m;
#pragma unroll
            for (int j = 0; j < 4; ++j) {
                const int ra = r0 + 4 * kg + j;
                if (ra < NN) Hb[(size_t)ra * 128 + n] = f2bf(acc[ct][j]);
            }
        }
    }
}

// ================= phase 2: merge src partials -> degout; scan dst partials -> bases, cnt =================
__global__ __launch_bounds__(256) void merge_scan(unsigned* __restrict__ psrc,
                                                  unsigned* __restrict__ pdst,
                                                  int* __restrict__ degout,
                                                  int* __restrict__ cnt) {
    const int idx = blockIdx.x * 256 + threadIdx.x;
    if (idx >= DEG_WORDS) return;
    {
        int a0 = 0, a1 = 0, a2 = 0, a3 = 0;
#pragma unroll 8
        for (int p = 0; p < SRC_BLK; ++p) {
            unsigned w = psrc[(size_t)p * DEG_WORDS + idx];
            a0 += w & 0xFF; a1 += (w >> 8) & 0xFF; a2 += (w >> 16) & 0xFF; a3 += (w >> 24);
        }
        ((int4*)degout)[idx] = make_int4(a0, a1, a2, a3);
    }
    {
        int r0 = 0, r1 = 0, r2 = 0, r3 = 0;
#pragma unroll 8
        for (int p = 0; p < DST_BLK; ++p) {
            const size_t o = (size_t)p * DEG_WORDS + idx;
            unsigned w = pdst[o];
            pdst[o] = (unsigned)r0 | ((unsigned)r1 << 8) | ((unsigned)r2 << 16) | ((unsigned)r3 << 24);
            r0 += w & 0xFF; r1 += (w >> 8) & 0xFF; r2 += (w >> 16) & 0xFF; r3 += (w >> 24);
        }
        ((int4*)cnt)[idx] = make_int4(r0, r1, r2, r3);
    }
}

// ================= phase 3 "fillc": slot-assign via LDS (hist preloaded with bases) =================
__global__ __launch_bounds__(256) void fillc_kernel(const int* __restrict__ src,
                                                    const int* __restrict__ dst,
                                                    const unsigned* __restrict__ pdst,
                                                    unsigned short* __restrict__ col) {
    __shared__ unsigned hist[DEG_WORDS];
    const int dblk = blockIdx.x;
    const int tid = threadIdx.x;
    const unsigned* bp = pdst + (size_t)dblk * DEG_WORDS;
    for (int i = tid; i < DEG_WORDS; i += 256) hist[i] = bp[i];
    __syncthreads();
    const int4* sp = (const int4*)(src + dblk * DST_CHUNK);
    const int4* dp = (const int4*)(dst + dblk * DST_CHUNK);
    for (int i = tid; i < DST_CHUNK / 4; i += 256) {
        int4 s = sp[i];
        int4 d = dp[i];
#pragma unroll
        for (int u = 0; u < 4; ++u) {
            const int dd = (u == 0) ? d.x : (u == 1) ? d.y : (u == 2) ? d.z : d.w;
            const int ss = (u == 0) ? s.x : (u == 1) ? s.y : (u == 2) ? s.z : s.w;
            const unsigned sh = (dd & 3) * 8;
            const unsigned old = atomicAdd(&hist[dd >> 2], 1u << sh);
            const int slot = (old >> sh) & 0xFF;
            col[dd * PAD + slot] = (unsigned short)ss;
        }
    }
}

// ---- LDS tile helpers (XOR-float4 swizzle; consistent write/read pair) ----
__device__ __forceinline__ void t_write4(float (*T)[128], int lr, int c, float4 v) {
    *(float4*)&T[lr][(((c >> 2) ^ (lr & 31)) << 2)] = v;
}
__device__ __forceinline__ void t_write(float (*T)[128], int lr, int n, float v) {
    T[lr][((((n >> 2) ^ (lr & 31)) << 2) | (n & 3))] = v;
}
__device__ __forceinline__ void split8_lds(const float (*T)[128], int lr, int c, bf16x8& h8, bf16x8& l8) {
    const int c4 = c >> 2, xr = lr & 31;
    float4 v0 = *(const float4*)&T[lr][(c4 ^ xr) << 2];
    float4 v1 = *(const float4*)&T[lr][((c4 + 1) ^ xr) << 2];
    float f[8] = {v0.x, v0.y, v0.z, v0.w, v1.x, v1.y, v1.z, v1.w};
#pragma unroll
    for (int i = 0; i < 8; ++i) {
        unsigned short h = f2bf(f[i]);
        h8[i] = (short)h;
        l8[i] = (short)f2bf(f[i] - bf2f(h));
    }
}

// ---- in-kernel ELL gather of 16 nodes into swizzled T (16 threads/node, 8 cols each) ----
// full chunks unmasked; tail chunk masked.
template <int SCALE_SRC>
__device__ __forceinline__ void gather16_to_T(
    float (*T)[128], const unsigned short* __restrict__ H,
    const int* __restrict__ cnt, const int* __restrict__ degout,
    const unsigned short* __restrict__ colp, const float* __restrict__ bias,
    int r0, int N, int tid) {
    const int nl = tid >> 4;        // local row 0..15
    const int q  = tid & 15;        // 8-col chunk
    int node = r0 + nl;
    node = (node < N) ? node : (N - 1);
    const int deg = cnt[node];
    const unsigned short* cl = colp + node * PAD;
    f32x4 acc0 = {0.f, 0.f, 0.f, 0.f};
    f32x4 acc1 = {0.f, 0.f, 0.f, 0.f};
    const int nfull = deg >> 3;
    for (int ch = 0; ch < nfull; ++ch) {
        const int jb = ch * 8;
        u16x8 si = *(const u16x8*)&cl[jb];
        u16x8 hv[8];
        float mm[8];
#pragma unroll
        for (int i = 0; i < 8; ++i) {
            const int s = si[i];
            hv[i] = *(const u16x8*)&H[(size_t)s * 128 + q * 8];
            if (SCALE_SRC) {
                int dg = degout[s];
                mm[i] = rsqrtf((float)(dg > 1 ? dg : 1));
            }
        }
#pragma unroll
        for (int i = 0; i < 8; ++i) {
#pragma unroll
            for (int k = 0; k < 4; ++k) {
                if (SCALE_SRC) {
                    acc0[k] = fmaf(bf2f((unsigned short)hv[i][k]), mm[i], acc0[k]);
                    acc1[k] = fmaf(bf2f((unsigned short)hv[i][4 + k]), mm[i], acc1[k]);
                } else {
                    acc0[k] += bf2f((unsigned short)hv[i][k]);
                    acc1[k] += bf2f((unsigned short)hv[i][4 + k]);
                }
            }
        }
    }
    const int rem = deg & 7;
    if (rem) {
        const int jb = nfull * 8;
        u16x8 si = *(const u16x8*)&cl[jb];
        u16x8 hv[8];
        float mm[8];
#pragma unroll
        for (int i = 0; i < 8; ++i) {
            const bool live = (i < rem);
            int s = live ? (int)si[i] : 0;   // pad loads hit cached row 0
            hv[i] = *(const u16x8*)&H[(size_t)s * 128 + q * 8];
            if (SCALE_SRC) {
                int dg = degout[s];
                float r = rsqrtf((float)(dg > 1 ? dg : 1));
                mm[i] = live ? r : 0.f;
            } else {
                mm[i] = live ? 1.f : 0.f;
            }
        }
#pragma unroll
        for (int i = 0; i < 8; ++i) {
#pragma unroll
            for (int k = 0; k < 4; ++k) {
                acc0[k] = fmaf(bf2f((unsigned short)hv[i][k]), mm[i], acc0[k]);
                acc1[k] = fmaf(bf2f((unsigned short)hv[i][4 + k]), mm[i], acc1[k]);
            }
        }
    }
    const float scv = rsqrtf((float)(deg > 1 ? deg : 1));
    const int c = q * 8;
    const float4 b0 = *(const float4*)&bias[c];
    const float4 b1 = *(const float4*)&bias[c + 4];
    float4 o0, o1;
    o0.x = fmaxf(acc0[0] * scv + b0.x, 0.f);
    o0.y = fmaxf(acc0[1] * scv + b0.y, 0.f);
    o0.z = fmaxf(acc0[2] * scv + b0.z, 0.f);
    o0.w = fmaxf(acc0[3] * scv + b0.w, 0.f);
    o1.x = fmaxf(acc1[0] * scv + b1.x, 0.f);
    o1.y = fmaxf(acc1[1] * scv + b1.y, 0.f);
    o1.z = fmaxf(acc1[2] * scv + b1.z, 0.f);
    o1.w = fmaxf(acc1[3] * scv + b1.w, 0.f);
    t_write4(T, nl, c, o0);
    t_write4(T, nl, c + 4, o1);
}

// one col-tile, sequential 3-MFMA chain
#define TILE(WH, WL) \
    f32x4 acc = {0.f, 0.f, 0.f, 0.f}; \
    _Pragma("unroll") \
    for (int ks = 0; ks < 4; ++ks) { \
        const size_t base = ((size_t)(CT * 4 + ks) * 64 + lane) * 8; \
        bf16x8 bh = *(const bf16x8*)&WH[base]; \
        bf16x8 bl = *(const bf16x8*)&WL[base]; \
        acc = __builtin_amdgcn_mfma_f32_16x16x32_bf16(ah[ks], bh, acc, 0, 0, 0); \
        acc = __builtin_amdgcn_mfma_f32_16x16x32_bf16(al[ks], bh, acc, 0, 0, 0); \
        acc = __builtin_amdgcn_mfma_f32_16x16x32_bf16(ah[ks], bl, acc, 0, 0, 0); \
    }

#define LOAD_FRAGS_FROM(TB) \
    _Pragma("unroll") \
    for (int ks = 0; ks < 4; ++ks) \
        split8_lds(TB, m, ks * 32 + kg * 8, ah[ks], al[ks]);

// ================= g0f3: gather0(+b0,relu,per-edge nsrc) -> fc1 -> fc2 -> @W1*nsrc =================
// 16-node blocks (3125); MFMA wave = 16 rows x 32 cols. Double-buffered T -> 3 barriers.
__global__ __launch_bounds__(256) void g0f3_kernel(
    const unsigned short* __restrict__ H,
    const int* __restrict__ cnt, const int* __restrict__ degout,
    const unsigned short* __restrict__ colp, const float* __restrict__ b0,
    const unsigned short* __restrict__ fwh, const unsigned short* __restrict__ fwl,
    const float* __restrict__ fcb,
    const unsigned short* __restrict__ f2h, const unsigned short* __restrict__ f2l,
    const float* __restrict__ fc2b,
    const unsigned short* __restrict__ w1h, const unsigned short* __restrict__ w1l,
    unsigned short* __restrict__ Yb, int N) {
    __shared__ float T[2][16][128];   // 16KB double-buffer
    const int tid = threadIdx.x;
    const int wave = tid >> 6;     // col quarter 0..3
    const int lane = tid & 63;
    const int m = lane & 15, kg = lane >> 4;
    const int r0 = blockIdx.x * 16;

    gather16_to_T<1>(T[0], H, cnt, degout, colp, b0, r0, N, tid);
    __syncthreads();

    bf16x8 ah[4], al[4];
    LOAD_FRAGS_FROM(T[0]);

    // ---- phase 1: @fcW, relu(+fcb) -> T[1] ----
#pragma unroll
    for (int ct = 0; ct < 2; ++ct) {
        const int CT = wave * 2 + ct;
        TILE(fwh, fwl)
        const int n = CT * 16 + m;
        const float bb = fcb[n];
#pragma unroll
        for (int j = 0; j < 4; ++j)
            t_write(T[1], 4 * kg + j, n, fmaxf(acc[j] + bb, 0.f));
    }
    __syncthreads();
    LOAD_FRAGS_FROM(T[1]);

    // ---- phase 2: @fc2W, relu(+fc2b) -> T[0] ----
#pragma unroll
    for (int ct = 0; ct < 2; ++ct) {
        const int CT = wave * 2 + ct;
        TILE(f2h, f2l)
        const int n = CT * 16 + m;
        const float bb = fc2b[n];
#pragma unroll
        for (int j = 0; j < 4; ++j)
            t_write(T[0], 4 * kg + j, n, fmaxf(acc[j] + bb, 0.f));
    }
    __syncthreads();
    LOAD_FRAGS_FROM(T[0]);

    // ---- phase 3: @W1, scale by rsqrt(degout) -> global bf16 ----
#pragma unroll
    for (int ct = 0; ct < 2; ++ct) {
        const int CT = wave * 2 + ct;
        TILE(w1h, w1l)
        const int n = CT * 16 + m;
#pragma unroll
        for (int j = 0; j < 4; ++j) {
            const int ra = r0 + 4 * kg + j;
            if (ra < N) {
                int dg = degout[ra];
                Yb[(size_t)ra * 128 + n] = f2bf(acc[j] * rsqrtf((float)(dg > 1 ? dg : 1)));
            }
        }
    }
}

// ================= g1g2: gather1(+b1,relu) -> @W2 * nsrc -> bf16 =================
__global__ __launch_bounds__(256) void g1g2_kernel(
    const unsigned short* __restrict__ H,
    const int* __restrict__ cnt, const int* __restrict__ degout,
    const unsigned short* __restrict__ colp, const float* __restrict__ b1,
    const unsigned short* __restrict__ w2h, const unsigned short* __restrict__ w2l,
    unsigned short* __restrict__ Yb, int N) {
    __shared__ float T[16][128];   // 8KB
    const int tid = threadIdx.x;
    const int wave = tid >> 6;
    const int lane = tid & 63;
    const int m = lane & 15, kg = lane >> 4;
    const int r0 = blockIdx.x * 16;

    gather16_to_T<0>(T, H, cnt, degout, colp, b1, r0, N, tid);
    __syncthreads();

    bf16x8 ah[4], al[4];
    LOAD_FRAGS_FROM(T);

    // @W2 (C=64): 1 col-tile per wave
    {
        const int CT = wave;
        TILE(w2h, w2l)
        const int n = CT * 16 + m;
#pragma unroll
        for (int j = 0; j < 4; ++j) {
            const int ra = r0 + 4 * kg + j;
            if (ra < N) {
                int dg = degout[ra];
                Yb[(size_t)ra * 64 + n] = f2bf(acc[j] * rsqrtf((float)(dg > 1 ? dg : 1)));
            }
        }
    }
}

// ================= standalone ELL gather (final layer, C=64, fp32 out) =================
__global__ __launch_bounds__(256) void gather2_kernel(
    const unsigned short* __restrict__ H, const int* __restrict__ cnt,
    const unsigned short* __restrict__ col,
    const float* __restrict__ bias, float* __restrict__ OUT, int N) {
    constexpr int C = 64, LPN = 8, NPB = 32;
    const int node = blockIdx.x * NPB + threadIdx.x / LPN;
    const int q = threadIdx.x % LPN;
    if (node >= N) return;
    const int deg = cnt[node];
    const unsigned short* cl = col + node * PAD;
    float acc[8];
#pragma unroll
    for (int k = 0; k < 8; ++k) acc[k] = 0.f;
    const int nfull = deg >> 3;
    for (int ch = 0; ch < nfull; ++ch) {
        const int jb = ch * 8;
        u16x8 si = *(const u16x8*)&cl[jb];
        u16x8 hv[8];
#pragma unroll
        for (int i = 0; i < 8; ++i) {
            const int s = si[i];
            hv[i] = *(const u16x8*)&H[(size_t)s * C + q * 8];
        }
#pragma unroll
        for (int i = 0; i < 8; ++i) {
#pragma unroll
            for (int k = 0; k < 8; ++k)
                acc[k] += bf2f((unsigned short)hv[i][k]);
        }
    }
    const int rem = deg & 7;
    if (rem) {
        const int jb = nfull * 8;
        u16x8 si = *(const u16x8*)&cl[jb];
        u16x8 hv[8];
        float mm[8];
#pragma unroll
        for (int i = 0; i < 8; ++i) {
            const bool live = (i < rem);
            int s = live ? (int)si[i] : 0;
            hv[i] = *(const u16x8*)&H[(size_t)s * C + q * 8];
            mm[i] = live ? 1.f : 0.f;
        }
#pragma unroll
        for (int i = 0; i < 8; ++i) {
#pragma unroll
            for (int k = 0; k < 8; ++k)
                acc[k] = fmaf(bf2f((unsigned short)hv[i][k]), mm[i], acc[k]);
        }
    }
    const float scv = rsqrtf((float)(deg > 1 ? deg : 1));
    const int cb = q * 8;
    float4 o0, o1;
    const float4 b0 = *(const float4*)&bias[cb];
    const float4 b1 = *(const float4*)&bias[cb + 4];
    o0.x = acc[0] * scv + b0.x; o0.y = acc[1] * scv + b0.y;
    o0.z = acc[2] * scv + b0.z; o0.w = acc[3] * scv + b0.w;
    o1.x = acc[4] * scv + b1.x; o1.y = acc[5] * scv + b1.y;
    o1.z = acc[6] * scv + b1.z; o1.w = acc[7] * scv + b1.w;
    *(float4*)&OUT[(size_t)node * C + cb] = o0;
    *(float4*)&OUT[(size_t)node * C + cb + 4] = o1;
}

extern "C" void kernel_launch(void* const* d_in, const int* in_sizes, int n_in,
                              void* d_out, int out_size, void* d_ws, size_t ws_size,
                              hipStream_t stream) {
    const float* x    = (const float*)d_in[0];
    const int*   src  = (const int*)d_in[1];
    const int*   dst  = (const int*)d_in[2];
    const float* W0   = (const float*)d_in[3];
    const float* b0   = (const float*)d_in[4];
    const float* fcW  = (const float*)d_in[5];
    const float* fcb  = (const float*)d_in[6];
    const float* fc2W = (const float*)d_in[7];
    const float* fc2b = (const float*)d_in[8];
    const float* W1   = (const float*)d_in[9];
    const float* b1   = (const float*)d_in[10];
    const float* W2   = (const float*)d_in[11];
    const float* b2   = (const float*)d_in[12];
    float* out = (float*)d_out;

    char* ws = (char*)d_ws;
    int* cnt    = (int*)ws;                                   // N i32 (in-degree)
    int* degout = cnt + NN;                                   // N i32 (out-degree)
    unsigned short* col = (unsigned short*)(degout + NN);     // N*PAD u16
    unsigned short* wp_hi = col + (size_t)NN * PAD;           // packed frags: fcW,fc2W,W1,W2
    unsigned short* wp_lo = wp_hi + CVW_ELEMS;
    size_t p = ((size_t)(2 * NN) * 4 + (size_t)NN * PAD * 2 + (size_t)CVW_ELEMS * 4 + 255) & ~(size_t)255;
    unsigned* psrc = (unsigned*)(ws + p);                     // SRC_BLK * 12500 u32
    unsigned* pdst = psrc + (size_t)SRC_BLK * DEG_WORDS;      // DST_BLK * 12500 u32
    size_t p1 = (p + (size_t)(SRC_BLK + DST_BLK) * DEG_WORDS * 4 + 255) & ~(size_t)255;
    unsigned short* Hb  = (unsigned short*)(ws + p1);         // N*128 bf16
    unsigned short* Hb2 = Hb + (size_t)NN * 128;              // N*128 bf16

    const unsigned short *fwh = wp_hi,          *fwl = wp_lo;
    const unsigned short *f2h = wp_hi + 16384,  *f2l = wp_lo + 16384;
    const unsigned short *w1h = wp_hi + 32768,  *w1l = wp_lo + 32768;
    const unsigned short *w2h = wp_hi + 49152,  *w2l = wp_lo + 49152;

    // ---- CSR build (atomic-free) + gemm0 + W packing ----
    hists_kernel<<<SRC_BLK + DST_BLK + CVW_BLK + GEMM0_BLK, 256, 0, stream>>>(
        src, dst, psrc, pdst, x, W0, Hb, fcW, fc2W, W1, W2, wp_hi, wp_lo);
    merge_scan<<<(DEG_WORDS + 255) / 256, 256, 0, stream>>>(psrc, pdst, degout, cnt);
    fillc_kernel<<<DST_BLK, 256, 0, stream>>>(src, dst, pdst, col);

    const int g16 = (NN + 15) / 16;              // 3125 blocks (16 nodes each)
    const int g32 = (NN + 31) / 32;              // 1563 blocks (gather2)

    // layer 0 + fc chain + @W1*nsrc: Hb -> Hb2
    g0f3_kernel<<<g16, 256, 0, stream>>>(Hb, cnt, degout, col, b0,
                                         fwh, fwl, fcb, f2h, f2l, fc2b, w1h, w1l, Hb2, NN);
    // layer 1 gather + @W2*nsrc: Hb2 -> Hb
    g1g2_kernel<<<g16, 256, 0, stream>>>(Hb2, cnt, degout, col, b1, w2h, w2l, Hb, NN);
    // final gather: Hb -> out (fp32, +b2, no relu)
    gather2_kernel<<<g32, 256, 0, stream>>>(Hb, cnt, col, b2, out, NN);
}

// Round 23
// 149.089 us; speedup vs baseline: 1.2973x; 1.2973x over previous
//
#include <hip/hip_runtime.h>
#include <hip/hip_bf16.h>

#define NN 50000
#define NE 800000
#define PAD 56   // ELL width: max in-degree for Poisson(16)/50K nodes ~38; 56 = +10 sigma

typedef __attribute__((ext_vector_type(8))) short bf16x8;
typedef __attribute__((ext_vector_type(4))) float f32x4;
typedef __attribute__((ext_vector_type(8))) unsigned short u16x8;

__device__ __forceinline__ unsigned short f2bf(float f) {
    __hip_bfloat16 h = __float2bfloat16(f);
    return *(unsigned short*)&h;
}
__device__ __forceinline__ float bf2f(unsigned short u) {
    unsigned int w = ((unsigned int)u) << 16;
    return __uint_as_float(w);
}

// split 8 consecutive floats into bf16 hi/lo fragments
__device__ __forceinline__ void split8(const float* __restrict__ p, bf16x8& h8, bf16x8& l8) {
    float4 v0 = *(const float4*)p;
    float4 v1 = *(const float4*)(p + 4);
    float f[8] = {v0.x, v0.y, v0.z, v0.w, v1.x, v1.y, v1.z, v1.w};
#pragma unroll
    for (int i = 0; i < 8; ++i) {
        unsigned short h = f2bf(f[i]);
        h8[i] = (short)h;
        l8[i] = (short)f2bf(f[i] - bf2f(h));
    }
}

// ================= phase 1 "hists": src/dst LDS histograms | gemm0 | W packing =================
#define SRC_BLK 64
#define SRC_CHUNK 12500   // NE / SRC_BLK
#define DST_BLK 160
#define DST_CHUNK 5000    // NE / DST_BLK
#define DEG_WORDS 12500   // NN/4 u32 words, 4 u8 bins per word (50KB LDS)
#define GEMM0_BLK 782     // ceil(NN/64), 16 rows/wave
#define CVW_ELEMS 57344   // fcW + fc2W + W1 (3*16384) + W2 (8192)
#define CVW_BLK 224

__global__ __launch_bounds__(256) void hists_kernel(
    const int* __restrict__ src, const int* __restrict__ dst,
    unsigned* __restrict__ psrc, unsigned* __restrict__ pdst,
    const float* __restrict__ x, const float* __restrict__ W0, unsigned short* __restrict__ Hb,
    const float* __restrict__ fcW, const float* __restrict__ fc2W,
    const float* __restrict__ W1, const float* __restrict__ W2,
    unsigned short* __restrict__ wp_hi, unsigned short* __restrict__ wp_lo) {
    __shared__ unsigned hist[DEG_WORDS];   // 50KB
    const int bid = blockIdx.x;
    const int tid = threadIdx.x;
    if (bid < SRC_BLK + DST_BLK) {
        const bool isSrc = bid < SRC_BLK;
        const int dblk = isSrc ? bid : bid - SRC_BLK;
        const int chunk = isSrc ? SRC_CHUNK : DST_CHUNK;
        const int* ep = isSrc ? (src + dblk * SRC_CHUNK) : (dst + dblk * DST_CHUNK);
        unsigned* outp = (isSrc ? psrc : pdst) + (size_t)dblk * DEG_WORDS;
        for (int i = tid; i < DEG_WORDS; i += 256) hist[i] = 0;
        __syncthreads();
        const int4* sp = (const int4*)ep;
        for (int i = tid; i < chunk / 4; i += 256) {
            int4 s = sp[i];
            atomicAdd(&hist[s.x >> 2], 1u << ((s.x & 3) * 8));
            atomicAdd(&hist[s.y >> 2], 1u << ((s.y & 3) * 8));
            atomicAdd(&hist[s.z >> 2], 1u << ((s.z & 3) * 8));
            atomicAdd(&hist[s.w >> 2], 1u << ((s.w & 3) * 8));
        }
        __syncthreads();
        for (int i = tid; i < DEG_WORDS; i += 256) outp[i] = hist[i];
    } else if (bid < SRC_BLK + DST_BLK + CVW_BLK) {
        int t = (bid - SRC_BLK - DST_BLK) * 256 + tid;
        if (t < CVW_ELEMS) {
            int mi = (t < 16384) ? 0 : (t < 32768) ? 1 : (t < 49152) ? 2 : 3;
            int beg = mi * 16384;
            int Cm = (mi == 3) ? 64 : 128;
            int loc = t - beg;
            int k = loc / Cm, c = loc % Cm;
            float v;
            switch (mi) {
                case 0: v = fcW[loc]; break;
                case 1: v = fc2W[loc]; break;
                case 2: v = W1[loc]; break;
                default: v = W2[loc]; break;
            }
            unsigned short h = f2bf(v);
            unsigned short l = f2bf(v - bf2f(h));
            int off = (((c >> 4) * 4 + (k >> 5)) * 64 + ((k & 31) >> 3) * 16 + (c & 15)) * 8 + (k & 7);
            wp_hi[beg + off] = h;
            wp_lo[beg + off] = l;
        }
    } else {
        // ---- gemm0: Hb = bf16(x @ W0), 16 rows/wave (r21 form: direct W0 reads) ----
        const int gb = bid - SRC_BLK - DST_BLK - CVW_BLK;
        const int wave = tid >> 6;
        const int lane = tid & 63;
        const int m = lane & 15, kg = lane >> 4;
        const int r0 = gb * 64 + wave * 16;
        int ar = r0 + m;
        ar = (ar < NN) ? ar : (NN - 1);

        bf16x8 ah[4], al[4];
#pragma unroll
        for (int ks = 0; ks < 4; ++ks)
            split8(&x[(size_t)ar * 128 + ks * 32 + kg * 8], ah[ks], al[ks]);

#pragma unroll
        for (int ct = 0; ct < 8; ++ct) {
            f32x4 acc = {0.f, 0.f, 0.f, 0.f};
            const int n = ct * 16 + m;
#pragma unroll
            for (int ks = 0; ks < 4; ++ks) {
                float w[8];
#pragma unroll
                for (int i = 0; i < 8; ++i)
                    w[i] = W0[(size_t)(ks * 32 + kg * 8 + i) * 128 + n];
                bf16x8 bh, bl;
#pragma unroll
                for (int i = 0; i < 8; ++i) {
                    unsigned short h = f2bf(w[i]);
                    bh[i] = (short)h;
                    bl[i] = (short)f2bf(w[i] - bf2f(h));
                }
                acc = __builtin_amdgcn_mfma_f32_16x16x32_bf16(ah[ks], bh, acc, 0, 0, 0);
                acc = __builtin_amdgcn_mfma_f32_16x16x32_bf16(al[ks], bh, acc, 0, 0, 0);
                acc = __builtin_amdgcn_mfma_f32_16x16x32_bf16(ah[ks], bl, acc, 0, 0, 0);
            }
#pragma unroll
            for (int j = 0; j < 4; ++j) {
                const int ra = r0 + 4 * kg + j;
                if (ra < NN) Hb[(size_t)ra * 128 + n] = f2bf(acc[j]);
            }
        }
    }
}

// ================= phase 2: merge src partials -> degout; scan dst partials -> bases, cnt =================
__global__ __launch_bounds__(256) void merge_scan(unsigned* __restrict__ psrc,
                                                  unsigned* __restrict__ pdst,
                                                  int* __restrict__ degout,
                                                  int* __restrict__ cnt) {
    const int idx = blockIdx.x * 256 + threadIdx.x;
    if (idx >= DEG_WORDS) return;
    {
        int a0 = 0, a1 = 0, a2 = 0, a3 = 0;
#pragma unroll 8
        for (int p = 0; p < SRC_BLK; ++p) {
            unsigned w = psrc[(size_t)p * DEG_WORDS + idx];
            a0 += w & 0xFF; a1 += (w >> 8) & 0xFF; a2 += (w >> 16) & 0xFF; a3 += (w >> 24);
        }
        ((int4*)degout)[idx] = make_int4(a0, a1, a2, a3);
    }
    {
        int r0 = 0, r1 = 0, r2 = 0, r3 = 0;
#pragma unroll 8
        for (int p = 0; p < DST_BLK; ++p) {
            const size_t o = (size_t)p * DEG_WORDS + idx;
            unsigned w = pdst[o];
            pdst[o] = (unsigned)r0 | ((unsigned)r1 << 8) | ((unsigned)r2 << 16) | ((unsigned)r3 << 24);
            r0 += w & 0xFF; r1 += (w >> 8) & 0xFF; r2 += (w >> 16) & 0xFF; r3 += (w >> 24);
        }
        ((int4*)cnt)[idx] = make_int4(r0, r1, r2, r3);
    }
}

// ================= phase 3 "fillc": slot-assign via LDS (hist preloaded with bases) =================
__global__ __launch_bounds__(256) void fillc_kernel(const int* __restrict__ src,
                                                    const int* __restrict__ dst,
                                                    const unsigned* __restrict__ pdst,
                                                    unsigned short* __restrict__ col) {
    __shared__ unsigned hist[DEG_WORDS];
    const int dblk = blockIdx.x;
    const int tid = threadIdx.x;
    const unsigned* bp = pdst + (size_t)dblk * DEG_WORDS;
    for (int i = tid; i < DEG_WORDS; i += 256) hist[i] = bp[i];
    __syncthreads();
    const int4* sp = (const int4*)(src + dblk * DST_CHUNK);
    const int4* dp = (const int4*)(dst + dblk * DST_CHUNK);
    for (int i = tid; i < DST_CHUNK / 4; i += 256) {
        int4 s = sp[i];
        int4 d = dp[i];
#pragma unroll
        for (int u = 0; u < 4; ++u) {
            const int dd = (u == 0) ? d.x : (u == 1) ? d.y : (u == 2) ? d.z : d.w;
            const int ss = (u == 0) ? s.x : (u == 1) ? s.y : (u == 2) ? s.z : s.w;
            const unsigned sh = (dd & 3) * 8;
            const unsigned old = atomicAdd(&hist[dd >> 2], 1u << sh);
            const int slot = (old >> sh) & 0xFF;
            col[dd * PAD + slot] = (unsigned short)ss;
        }
    }
}

// ---- LDS tile helpers (XOR-float4 swizzle; consistent write/read pair) ----
__device__ __forceinline__ void t_write4(float (*T)[128], int lr, int c, float4 v) {
    *(float4*)&T[lr][(((c >> 2) ^ (lr & 31)) << 2)] = v;
}
__device__ __forceinline__ void t_write(float (*T)[128], int lr, int n, float v) {
    T[lr][((((n >> 2) ^ (lr & 31)) << 2) | (n & 3))] = v;
}
__device__ __forceinline__ void split8_lds(const float (*T)[128], int lr, int c, bf16x8& h8, bf16x8& l8) {
    const int c4 = c >> 2, xr = lr & 31;
    float4 v0 = *(const float4*)&T[lr][(c4 ^ xr) << 2];
    float4 v1 = *(const float4*)&T[lr][((c4 + 1) ^ xr) << 2];
    float f[8] = {v0.x, v0.y, v0.z, v0.w, v1.x, v1.y, v1.z, v1.w};
#pragma unroll
    for (int i = 0; i < 8; ++i) {
        unsigned short h = f2bf(f[i]);
        h8[i] = (short)h;
        l8[i] = (short)f2bf(f[i] - bf2f(h));
    }
}

// ---- in-kernel ELL gather of 16 nodes into swizzled T (16 threads/node, 8 cols each) ----
// full chunks unmasked; tail chunk masked.
template <int SCALE_SRC>
__device__ __forceinline__ void gather16_to_T(
    float (*T)[128], const unsigned short* __restrict__ H,
    const int* __restrict__ cnt, const int* __restrict__ degout,
    const unsigned short* __restrict__ colp, const float* __restrict__ bias,
    int r0, int N, int tid) {
    const int nl = tid >> 4;        // local row 0..15
    const int q  = tid & 15;        // 8-col chunk
    int node = r0 + nl;
    node = (node < N) ? node : (N - 1);
    const int deg = cnt[node];
    const unsigned short* cl = colp + node * PAD;
    f32x4 acc0 = {0.f, 0.f, 0.f, 0.f};
    f32x4 acc1 = {0.f, 0.f, 0.f, 0.f};
    const int nfull = deg >> 3;
    for (int ch = 0; ch < nfull; ++ch) {
        const int jb = ch * 8;
        u16x8 si = *(const u16x8*)&cl[jb];
        u16x8 hv[8];
        float mm[8];
#pragma unroll
        for (int i = 0; i < 8; ++i) {
            const int s = si[i];
            hv[i] = *(const u16x8*)&H[(size_t)s * 128 + q * 8];
            if (SCALE_SRC) {
                int dg = degout[s];
                mm[i] = rsqrtf((float)(dg > 1 ? dg : 1));
            }
        }
#pragma unroll
        for (int i = 0; i < 8; ++i) {
#pragma unroll
            for (int k = 0; k < 4; ++k) {
                if (SCALE_SRC) {
                    acc0[k] = fmaf(bf2f((unsigned short)hv[i][k]), mm[i], acc0[k]);
                    acc1[k] = fmaf(bf2f((unsigned short)hv[i][4 + k]), mm[i], acc1[k]);
                } else {
                    acc0[k] += bf2f((unsigned short)hv[i][k]);
                    acc1[k] += bf2f((unsigned short)hv[i][4 + k]);
                }
            }
        }
    }
    const int rem = deg & 7;
    if (rem) {
        const int jb = nfull * 8;
        u16x8 si = *(const u16x8*)&cl[jb];
        u16x8 hv[8];
        float mm[8];
#pragma unroll
        for (int i = 0; i < 8; ++i) {
            const bool live = (i < rem);
            int s = live ? (int)si[i] : 0;   // pad loads hit cached row 0
            hv[i] = *(const u16x8*)&H[(size_t)s * 128 + q * 8];
            if (SCALE_SRC) {
                int dg = degout[s];
                float r = rsqrtf((float)(dg > 1 ? dg : 1));
                mm[i] = live ? r : 0.f;
            } else {
                mm[i] = live ? 1.f : 0.f;
            }
        }
#pragma unroll
        for (int i = 0; i < 8; ++i) {
#pragma unroll
            for (int k = 0; k < 4; ++k) {
                acc0[k] = fmaf(bf2f((unsigned short)hv[i][k]), mm[i], acc0[k]);
                acc1[k] = fmaf(bf2f((unsigned short)hv[i][4 + k]), mm[i], acc1[k]);
            }
        }
    }
    const float scv = rsqrtf((float)(deg > 1 ? deg : 1));
    const int c = q * 8;
    const float4 b0 = *(const float4*)&bias[c];
    const float4 b1 = *(const float4*)&bias[c + 4];
    float4 o0, o1;
    o0.x = fmaxf(acc0[0] * scv + b0.x, 0.f);
    o0.y = fmaxf(acc0[1] * scv + b0.y, 0.f);
    o0.z = fmaxf(acc0[2] * scv + b0.z, 0.f);
    o0.w = fmaxf(acc0[3] * scv + b0.w, 0.f);
    o1.x = fmaxf(acc1[0] * scv + b1.x, 0.f);
    o1.y = fmaxf(acc1[1] * scv + b1.y, 0.f);
    o1.z = fmaxf(acc1[2] * scv + b1.z, 0.f);
    o1.w = fmaxf(acc1[3] * scv + b1.w, 0.f);
    t_write4(T, nl, c, o0);
    t_write4(T, nl, c + 4, o1);
}

// one col-tile, sequential 3-MFMA chain
#define TILE(WH, WL) \
    f32x4 acc = {0.f, 0.f, 0.f, 0.f}; \
    _Pragma("unroll") \
    for (int ks = 0; ks < 4; ++ks) { \
        const size_t base = ((size_t)(CT * 4 + ks) * 64 + lane) * 8; \
        bf16x8 bh = *(const bf16x8*)&WH[base]; \
        bf16x8 bl = *(const bf16x8*)&WL[base]; \
        acc = __builtin_amdgcn_mfma_f32_16x16x32_bf16(ah[ks], bh, acc, 0, 0, 0); \
        acc = __builtin_amdgcn_mfma_f32_16x16x32_bf16(al[ks], bh, acc, 0, 0, 0); \
        acc = __builtin_amdgcn_mfma_f32_16x16x32_bf16(ah[ks], bl, acc, 0, 0, 0); \
    }

#define LOAD_FRAGS_FROM(TB) \
    _Pragma("unroll") \
    for (int ks = 0; ks < 4; ++ks) \
        split8_lds(TB, m, ks * 32 + kg * 8, ah[ks], al[ks]);

// ================= g0f3: gather0(+b0,relu,per-edge nsrc) -> fc1 -> fc2 -> @W1*nsrc =================
// 16-node blocks (3125); MFMA wave = 16 rows x 32 cols. Double-buffered T -> 4 barriers total.
__global__ __launch_bounds__(256) void g0f3_kernel(
    const unsigned short* __restrict__ H,
    const int* __restrict__ cnt, const int* __restrict__ degout,
    const unsigned short* __restrict__ colp, const float* __restrict__ b0,
    const unsigned short* __restrict__ fwh, const unsigned short* __restrict__ fwl,
    const float* __restrict__ fcb,
    const unsigned short* __restrict__ f2h, const unsigned short* __restrict__ f2l,
    const float* __restrict__ fc2b,
    const unsigned short* __restrict__ w1h, const unsigned short* __restrict__ w1l,
    unsigned short* __restrict__ Yb, int N) {
    __shared__ float T[2][16][128];   // 16KB double-buffer
    const int tid = threadIdx.x;
    const int wave = tid >> 6;     // col quarter 0..3
    const int lane = tid & 63;
    const int m = lane & 15, kg = lane >> 4;
    const int r0 = blockIdx.x * 16;

    gather16_to_T<1>(T[0], H, cnt, degout, colp, b0, r0, N, tid);
    __syncthreads();

    bf16x8 ah[4], al[4];
    LOAD_FRAGS_FROM(T[0]);

    // ---- phase 1: @fcW, relu(+fcb) -> T[1] ----
#pragma unroll
    for (int ct = 0; ct < 2; ++ct) {
        const int CT = wave * 2 + ct;
        TILE(fwh, fwl)
        const int n = CT * 16 + m;
        const float bb = fcb[n];
#pragma unroll
        for (int j = 0; j < 4; ++j)
            t_write(T[1], 4 * kg + j, n, fmaxf(acc[j] + bb, 0.f));
    }
    __syncthreads();
    LOAD_FRAGS_FROM(T[1]);

    // ---- phase 2: @fc2W, relu(+fc2b) -> T[0] ----
#pragma unroll
    for (int ct = 0; ct < 2; ++ct) {
        const int CT = wave * 2 + ct;
        TILE(f2h, f2l)
        const int n = CT * 16 + m;
        const float bb = fc2b[n];
#pragma unroll
        for (int j = 0; j < 4; ++j)
            t_write(T[0], 4 * kg + j, n, fmaxf(acc[j] + bb, 0.f));
    }
    __syncthreads();
    LOAD_FRAGS_FROM(T[0]);

    // ---- phase 3: @W1, scale by rsqrt(degout) -> global bf16 ----
#pragma unroll
    for (int ct = 0; ct < 2; ++ct) {
        const int CT = wave * 2 + ct;
        TILE(w1h, w1l)
        const int n = CT * 16 + m;
#pragma unroll
        for (int j = 0; j < 4; ++j) {
            const int ra = r0 + 4 * kg + j;
            if (ra < N) {
                int dg = degout[ra];
                Yb[(size_t)ra * 128 + n] = f2bf(acc[j] * rsqrtf((float)(dg > 1 ? dg : 1)));
            }
        }
    }
}

// ================= g1g2: gather1(+b1,relu) -> @W2 * nsrc -> bf16 =================
__global__ __launch_bounds__(256) void g1g2_kernel(
    const unsigned short* __restrict__ H,
    const int* __restrict__ cnt, const int* __restrict__ degout,
    const unsigned short* __restrict__ colp, const float* __restrict__ b1,
    const unsigned short* __restrict__ w2h, const unsigned short* __restrict__ w2l,
    unsigned short* __restrict__ Yb, int N) {
    __shared__ float T[16][128];   // 8KB
    const int tid = threadIdx.x;
    const int wave = tid >> 6;
    const int lane = tid & 63;
    const int m = lane & 15, kg = lane >> 4;
    const int r0 = blockIdx.x * 16;

    gather16_to_T<0>(T, H, cnt, degout, colp, b1, r0, N, tid);
    __syncthreads();

    bf16x8 ah[4], al[4];
    LOAD_FRAGS_FROM(T);

    // @W2 (C=64): 1 col-tile per wave
    {
        const int CT = wave;
        TILE(w2h, w2l)
        const int n = CT * 16 + m;
#pragma unroll
        for (int j = 0; j < 4; ++j) {
            const int ra = r0 + 4 * kg + j;
            if (ra < N) {
                int dg = degout[ra];
                Yb[(size_t)ra * 64 + n] = f2bf(acc[j] * rsqrtf((float)(dg > 1 ? dg : 1)));
            }
        }
    }
}

// ================= standalone ELL gather (final layer, C=64, fp32 out) =================
__global__ __launch_bounds__(256) void gather2_kernel(
    const unsigned short* __restrict__ H, const int* __restrict__ cnt,
    const unsigned short* __restrict__ col,
    const float* __restrict__ bias, float* __restrict__ OUT, int N) {
    constexpr int C = 64, LPN = 8, NPB = 32;
    const int node = blockIdx.x * NPB + threadIdx.x / LPN;
    const int q = threadIdx.x % LPN;
    if (node >= N) return;
    const int deg = cnt[node];
    const unsigned short* cl = col + node * PAD;
    float acc[8];
#pragma unroll
    for (int k = 0; k < 8; ++k) acc[k] = 0.f;
    const int nfull = deg >> 3;
    for (int ch = 0; ch < nfull; ++ch) {
        const int jb = ch * 8;
        u16x8 si = *(const u16x8*)&cl[jb];
        u16x8 hv[8];
#pragma unroll
        for (int i = 0; i < 8; ++i) {
            const int s = si[i];
            hv[i] = *(const u16x8*)&H[(size_t)s * C + q * 8];
        }
#pragma unroll
        for (int i = 0; i < 8; ++i) {
#pragma unroll
            for (int k = 0; k < 8; ++k)
                acc[k] += bf2f((unsigned short)hv[i][k]);
        }
    }
    const int rem = deg & 7;
    if (rem) {
        const int jb = nfull * 8;
        u16x8 si = *(const u16x8*)&cl[jb];
        u16x8 hv[8];
        float mm[8];
#pragma unroll
        for (int i = 0; i < 8; ++i) {
            const bool live = (i < rem);
            int s = live ? (int)si[i] : 0;
            hv[i] = *(const u16x8*)&H[(size_t)s * C + q * 8];
            mm[i] = live ? 1.f : 0.f;
        }
#pragma unroll
        for (int i = 0; i < 8; ++i) {
#pragma unroll
            for (int k = 0; k < 8; ++k)
                acc[k] = fmaf(bf2f((unsigned short)hv[i][k]), mm[i], acc[k]);
        }
    }
    const float scv = rsqrtf((float)(deg > 1 ? deg : 1));
    const int cb = q * 8;
    float4 o0, o1;
    const float4 b0 = *(const float4*)&bias[cb];
    const float4 b1 = *(const float4*)&bias[cb + 4];
    o0.x = acc[0] * scv + b0.x; o0.y = acc[1] * scv + b0.y;
    o0.z = acc[2] * scv + b0.z; o0.w = acc[3] * scv + b0.w;
    o1.x = acc[4] * scv + b1.x; o1.y = acc[5] * scv + b1.y;
    o1.z = acc[6] * scv + b1.z; o1.w = acc[7] * scv + b1.w;
    *(float4*)&OUT[(size_t)node * C + cb] = o0;
    *(float4*)&OUT[(size_t)node * C + cb + 4] = o1;
}

extern "C" void kernel_launch(void* const* d_in, const int* in_sizes, int n_in,
                              void* d_out, int out_size, void* d_ws, size_t ws_size,
                              hipStream_t stream) {
    const float* x    = (const float*)d_in[0];
    const int*   src  = (const int*)d_in[1];
    const int*   dst  = (const int*)d_in[2];
    const float* W0   = (const float*)d_in[3];
    const float* b0   = (const float*)d_in[4];
    const float* fcW  = (const float*)d_in[5];
    const float* fcb  = (const float*)d_in[6];
    const float* fc2W = (const float*)d_in[7];
    const float* fc2b = (const float*)d_in[8];
    const float* W1   = (const float*)d_in[9];
    const float* b1   = (const float*)d_in[10];
    const float* W2   = (const float*)d_in[11];
    const float* b2   = (const float*)d_in[12];
    float* out = (float*)d_out;

    char* ws = (char*)d_ws;
    int* cnt    = (int*)ws;                                   // N i32 (in-degree)
    int* degout = cnt + NN;                                   // N i32 (out-degree)
    unsigned short* col = (unsigned short*)(degout + NN);     // N*PAD u16
    unsigned short* wp_hi = col + (size_t)NN * PAD;           // packed frags: fcW,fc2W,W1,W2
    unsigned short* wp_lo = wp_hi + CVW_ELEMS;
    size_t p = ((size_t)(2 * NN) * 4 + (size_t)NN * PAD * 2 + (size_t)CVW_ELEMS * 4 + 255) & ~(size_t)255;
    unsigned* psrc = (unsigned*)(ws + p);                     // SRC_BLK * 12500 u32
    unsigned* pdst = psrc + (size_t)SRC_BLK * DEG_WORDS;      // DST_BLK * 12500 u32
    size_t p1 = (p + (size_t)(SRC_BLK + DST_BLK) * DEG_WORDS * 4 + 255) & ~(size_t)255;
    unsigned short* Hb  = (unsigned short*)(ws + p1);         // N*128 bf16
    unsigned short* Hb2 = Hb + (size_t)NN * 128;              // N*128 bf16

    const unsigned short *fwh = wp_hi,          *fwl = wp_lo;
    const unsigned short *f2h = wp_hi + 16384,  *f2l = wp_lo + 16384;
    const unsigned short *w1h = wp_hi + 32768,  *w1l = wp_lo + 32768;
    const unsigned short *w2h = wp_hi + 49152,  *w2l = wp_lo + 49152;

    // ---- CSR build (atomic-free) + gemm0 + W packing ----
    hists_kernel<<<SRC_BLK + DST_BLK + CVW_BLK + GEMM0_BLK, 256, 0, stream>>>(
        src, dst, psrc, pdst, x, W0, Hb, fcW, fc2W, W1, W2, wp_hi, wp_lo);
    merge_scan<<<(DEG_WORDS + 255) / 256, 256, 0, stream>>>(psrc, pdst, degout, cnt);
    fillc_kernel<<<DST_BLK, 256, 0, stream>>>(src, dst, pdst, col);

    const int g16 = (NN + 15) / 16;              // 3125 blocks (16 nodes each)
    const int g32 = (NN + 31) / 32;              // 1563 blocks (gather2)

    // layer 0 + fc chain + @W1*nsrc: Hb -> Hb2
    g0f3_kernel<<<g16, 256, 0, stream>>>(Hb, cnt, degout, col, b0,
                                         fwh, fwl, fcb, f2h, f2l, fc2b, w1h, w1l, Hb2, NN);
    // layer 1 gather + @W2*nsrc: Hb2 -> Hb
    g1g2_kernel<<<g16, 256, 0, stream>>>(Hb2, cnt, degout, col, b1, w2h, w2l, Hb, NN);
    // final gather: Hb -> out (fp32, +b2, no relu)
    gather2_kernel<<<g32, 256, 0, stream>>>(Hb, cnt, col, b2, out, NN);
}